// Round 11
// baseline (173.848 us; speedup 1.0000x reference)
//
#include <hip/hip_runtime.h>
#include <math.h>

// Problem constants
#define NRAYS        32768
#define MARCH_ITERS  64
#define EPS_         1e-4f
#define STEP_        ((1.0f + 1.0f/64.0f) / 64.0f)   // exact in fp32

typedef __attribute__((ext_vector_type(8)))  short    short8;   // 8 bf16
typedef __attribute__((ext_vector_type(4)))  float    float4v;  // C/D frag
typedef __attribute__((ext_vector_type(2)))  float    float2v;  // pk-f32 pair
typedef __attribute__((ext_vector_type(4)))  unsigned uint4v;

__device__ __forceinline__ short8 mk_frag(unsigned p0, unsigned p1,
                                          unsigned p2, unsigned p3) {
    uint4v v = {p0, p1, p2, p3};
    return __builtin_bit_cast(short8, v);
}

// One v_perm_b32: low16 = trunc-bf16(a), high16 = trunc-bf16(b).
__device__ __forceinline__ unsigned packbf(unsigned a, unsigned b) {
    return __builtin_amdgcn_perm(b, a, 0x07060302u);
}

// 2-way split: hi + residual (packbf of r truncates -> the mid limb).
struct Split2 { unsigned h, r; };
__device__ __forceinline__ Split2 split2(float x) {
    unsigned xu = __float_as_uint(x);
    float xh = __uint_as_float(xu & 0xFFFF0000u);
    float rr = x - xh;                        // exact residual
    return { xu, __float_as_uint(rr) };
}

// packed f32 fma -> v_pk_fma_f32 (lane-exact == 2 scalar v_fma_f32)
__device__ __forceinline__ float2v fma2(float2v a, float2v b, float2v c) {
    return __builtin_elementwise_fma(a, b, c);
}

// Cross-lane butterflies (R24-verified): swizzle xor16 + shfl xor32.
__device__ __forceinline__ float xor16_sum(float x) {
    float p = __int_as_float(
        __builtin_amdgcn_ds_swizzle(__float_as_int(x), 0x401F));
    return x + p;
}
__device__ __forceinline__ float xor32_sum(float x) {
    return x + __shfl_xor(x, 32, 64);
}

// R25: break the MFMA C-accumulator chains. R24 post-mortem: pipeline
// deepening was null (118 vs 114); per-SIMD per-iter span ~4275 cyc vs
// only ~1550 matrix + ~840 VALU of pipe work -- the unexplained stall
// scales with the count of DEPENDENT MFMA stages (march chained all 24
// MFMAs through ONE accumulator = 6 serial stages; tput 4), and
// dependent-MFMA latency is the one HW term with no measurement
// (guide: "MFMA latency not isolated"). Fix: the march limb products
// (m*h, h*m, h*h) are independent until summed -- give each its own
// accumulator (C2a/C2b/C2c, 2 internal stages each; tput C2x/C2y) and
// combine with pk-f32 adds before l3. March MFMA critical depth 6->2,
// tput 4->2; the parallel chains interleave in the matrix pipe.
// Numerics: fp32 summation regrouping only -> O(ulp) shift; threshold
// headroom 3x (0.0039 vs 0.0112). Everything else identical to R24
// (fused march+tput, 1-deep tput pipeline, linear-L1, pk packing,
// verified butterflies).
// 2048 single-wave blocks, 16 rays each; waves_per_eu(2,2): exactly
// 2 waves/SIMD resident, 256-reg budget pinned (WRITE_SIZE ~512KB is
// the spill tripwire).
// MFMA layouts (R6-verified): A[row=lane&15][k=quad*8+j],
// B[k=quad*8+j][col=lane&15], C/D col=lane&15 row=quad*4+reg.
// Precision: march L2 = 3 products (m,h)(h,m)(h,h); tput L2 = 2 products.
__global__ __launch_bounds__(64)
__attribute__((amdgpu_waves_per_eu(2, 2)))
void sdf_w14_k(
    const float* __restrict__ rays,
    const float* __restrict__ W0,  const float* __restrict__ b0,
    const float* __restrict__ W1,  const float* __restrict__ b1,
    const float* __restrict__ W2,  const float* __restrict__ b2,
    const float* __restrict__ Wr0, const float* __restrict__ br0,
    const float* __restrict__ Wr1, const float* __restrict__ br1,
    float* __restrict__ out)
{
    const int lane = threadIdx.x;             // 0..63, one wave per block
    const int quad = lane >> 4;
    const int m    = lane & 15;
    const int rayBase = blockIdx.x * 16;

    // ---- per-lane ray (ray = rayBase + m, replicated over quads) ----
    const float* rp = rays + (rayBase + m) * 6;
    const float ox = rp[0], oy = rp[1], oz = rp[2];
    const float dx = rp[3], dy = rp[4], dz = rp[5];

    // ---- linear-L1 coefficients (R21): L1 pre-act = a + c*s ----
    float2v a2[4][2], s2[4][2];
    #pragma unroll
    for (int t = 0; t < 4; ++t)
        #pragma unroll
        for (int p = 0; p < 2; ++p) {
            float av[2], sv[2];
            #pragma unroll
            for (int e = 0; e < 2; ++e) {
                int j = 32 * (t >> 1) + 8 * quad + 4 * (t & 1) + (2 * p + e);
                float w0c = W0[j], w1c = W0[64 + j], w2c = W0[128 + j];
                av[e] = fmaf(ox, w0c, fmaf(oy, w1c, fmaf(oz, w2c, b0[j])));
                sv[e] = fmaf(dx, w0c, fmaf(dy, w1c, dz * w2c));
            }
            a2[t][p] = (float2v){av[0], av[1]};
            s2[t][p] = (float2v){sv[0], sv[1]};
        }

    // ---- b1 (first-product C-input) and W2 (L3), rows j2 = 16t+4q+r ----
    float4v b1v[4];
    float2v w2a[4], w2b[4];
    #pragma unroll
    for (int t = 0; t < 4; ++t) {
        int base = 16 * t + 4 * quad;
        b1v[t] = (float4v){b1[base], b1[base + 1], b1[base + 2], b1[base + 3]};
        w2a[t] = (float2v){W2[base], W2[base + 1]};
        w2b[t] = (float2v){W2[base + 2], W2[base + 3]};
    }
    const float b2s = b2[0];
    const float4v z4 = {0.f, 0.f, 0.f, 0.f};

    // ---- W1 limbs: A2h (hi) + A2m (mid), 64 regs, shared by streams ----
    short8 A2h[2][4], A2m[2][4];
    #pragma unroll
    for (int h = 0; h < 2; ++h)
        #pragma unroll
        for (int t = 0; t < 4; ++t) {
            unsigned pm[4], ph[4];
            #pragma unroll
            for (int jp = 0; jp < 4; ++jp) {
                int k0 = 32 * h + quad * 8 + 2 * jp;
                int j2 = 16 * t + m;
                Split2 a = split2(W1[k0 * 64 + j2]);
                Split2 b = split2(W1[(k0 + 1) * 64 + j2]);
                pm[jp] = packbf(a.r, b.r);   // trunc(residual) == mid limb
                ph[jp] = packbf(a.h, b.h);   // trunc(full) == hi limb
            }
            A2m[h][t] = mk_frag(pm[0], pm[1], pm[2], pm[3]);
            A2h[h][t] = mk_frag(ph[0], ph[1], ph[2], ph[3]);
        }

    // ---- shared front-end: c -> L1 = relu(a + c*s) -> split2 pack ----
    const float2v z2 = {0.f, 0.f};
    auto front = [&](float cv, short8* BH, short8* BM) {
        const float2v c2 = {cv, cv};
        unsigned PH[4][2], PM[4][2];
        #pragma unroll
        for (int t = 0; t < 4; ++t) {
            float2v v01 = fma2(c2, s2[t][0], a2[t][0]);
            float2v v23 = fma2(c2, s2[t][1], a2[t][1]);
            v01 = __builtin_elementwise_max(v01, z2);
            v23 = __builtin_elementwise_max(v23, z2);
            unsigned u0 = __float_as_uint(v01.x), u1 = __float_as_uint(v01.y);
            unsigned u2 = __float_as_uint(v23.x), u3 = __float_as_uint(v23.y);
            PH[t][0] = packbf(u0, u1); PH[t][1] = packbf(u2, u3);
            float2v h01 = {__uint_as_float(u0 & 0xFFFF0000u),
                           __uint_as_float(u1 & 0xFFFF0000u)};
            float2v h23 = {__uint_as_float(u2 & 0xFFFF0000u),
                           __uint_as_float(u3 & 0xFFFF0000u)};
            float2v r01 = v01 - h01;   // pk sub, exact residual
            float2v r23 = v23 - h23;
            PM[t][0] = packbf(__float_as_uint(r01.x), __float_as_uint(r01.y));
            PM[t][1] = packbf(__float_as_uint(r23.x), __float_as_uint(r23.y));
        }
        #pragma unroll
        for (int h = 0; h < 2; ++h) {
            BH[h] = mk_frag(PH[2 * h][0], PH[2 * h][1],
                            PH[2 * h + 1][0], PH[2 * h + 1][1]);
            BM[h] = mk_frag(PM[2 * h][0], PM[2 * h][1],
                            PM[2 * h + 1][0], PM[2 * h + 1][1]);
        }
    };

    // ---- L3: in-lane relu*W2 (pk fma), verified cross-lane reduce ----
    auto l3 = [&](const float4v* C2) -> float {
        float2v q01 = {0.f, 0.f}, q23 = {0.f, 0.f};
        #pragma unroll
        for (int t = 0; t < 4; ++t) {
            float2v rel01 = __builtin_elementwise_max(
                (float2v){C2[t][0], C2[t][1]}, z2);
            float2v rel23 = __builtin_elementwise_max(
                (float2v){C2[t][2], C2[t][3]}, z2);
            q01 = fma2(rel01, w2a[t], q01);
            q23 = fma2(rel23, w2b[t], q23);
        }
        float part = (q01.x + q01.y) + (q23.x + q23.y);
        part = xor16_sum(part);                // == part + shfl_xor(part,16)
        part = xor32_sum(part);                // == part + shfl_xor(part,32)
        return b2s + part;
    };

    // tput L2: 2 INDEPENDENT products (depth 2 each), combined at the end.
    auto tputC2 = [&](const short8* BHt, const short8* BMt, float4v* C2t) {
        float4v Cx[4], Cy[4];
        #pragma unroll
        for (int t = 0; t < 4; ++t) {
            Cx[t] = __builtin_amdgcn_mfma_f32_16x16x32_bf16(
                A2h[0][t], BMt[0], b1v[t], 0, 0, 0);
            Cy[t] = __builtin_amdgcn_mfma_f32_16x16x32_bf16(
                A2h[0][t], BHt[0], z4, 0, 0, 0);
        }
        #pragma unroll
        for (int t = 0; t < 4; ++t) {
            Cx[t] = __builtin_amdgcn_mfma_f32_16x16x32_bf16(
                A2h[1][t], BMt[1], Cx[t], 0, 0, 0);
            Cy[t] = __builtin_amdgcn_mfma_f32_16x16x32_bf16(
                A2h[1][t], BHt[1], Cy[t], 0, 0, 0);
        }
        #pragma unroll
        for (int t = 0; t < 4; ++t)
            C2t[t] = Cx[t] + Cy[t];            // pk-f32 adds
    };

    bool  hit = false;
    float cd  = 0.f;
    float cm  = 3.4e38f;
    int   i   = 0;

    // tput software pipeline, 1 deep: BHt/BMt always hold eval i.
    short8 BHt[2], BMt[2];
    front(0.f, BHt, BMt);                     // eval 0 (t = 0 at origin)

    // =========== FUSED loop: march iter i + tput eval i ==================
    #pragma unroll 1
    for (; i < MARCH_ITERS; ++i) {
        if (__all(hit)) break;                 // BHt still holds eval i
        // 1) tput MFMAs for eval i (independent; fills cd->front_m gap)
        float4v C2t[4];
        tputC2(BHt, BMt, C2t);
        // 2) produce next tput front (independent filler for march chain)
        short8 BHtN[2], BMtN[2];
        front(STEP_ * (float)(i + 1), BHtN, BMtN);
        // 3) march front + 3 INDEPENDENT 2-stage limb products:
        //    C2a = b1 + (m,h); C2b = (h,m); C2c = (h,h). Critical MFMA
        //    depth 2 (was 6); chains interleave in the matrix pipe.
        short8 BHm[2], BMm[2];
        front(cd, BHm, BMm);
        float4v C2a[4], C2b[4], C2c[4];
        #pragma unroll
        for (int t = 0; t < 4; ++t) {
            C2a[t] = __builtin_amdgcn_mfma_f32_16x16x32_bf16(
                A2m[0][t], BHm[0], b1v[t], 0, 0, 0);
            C2b[t] = __builtin_amdgcn_mfma_f32_16x16x32_bf16(
                A2h[0][t], BMm[0], z4, 0, 0, 0);
            C2c[t] = __builtin_amdgcn_mfma_f32_16x16x32_bf16(
                A2h[0][t], BHm[0], z4, 0, 0, 0);
        }
        #pragma unroll
        for (int t = 0; t < 4; ++t) {
            C2a[t] = __builtin_amdgcn_mfma_f32_16x16x32_bf16(
                A2m[1][t], BHm[1], C2a[t], 0, 0, 0);
            C2b[t] = __builtin_amdgcn_mfma_f32_16x16x32_bf16(
                A2h[1][t], BMm[1], C2b[t], 0, 0, 0);
            C2c[t] = __builtin_amdgcn_mfma_f32_16x16x32_bf16(
                A2h[1][t], BHm[1], C2c[t], 0, 0, 0);
        }
        float4v C2m[4];
        #pragma unroll
        for (int t = 0; t < 4; ++t)
            C2m[t] = (C2a[t] + C2b[t]) + C2c[t];   // pk-f32 adds
        // 4) march finish (serial chain; tput MFMAs drain underneath)
        float dm = l3(C2m);
        bool c = (dm < EPS_) && (cd >= 0.f) && (cd <= 1.f);
        hit = hit || c;
        if (!hit) cd += dm;
        // 5) tput finish + rotate pipeline buffers
        cm = fminf(cm, l3(C2t));
        BHt[0] = BHtN[0]; BHt[1] = BHtN[1];
        BMt[0] = BMtN[0]; BMt[1] = BMtN[1];
    }

    // =========== tput-only remainder (march done / all-hit) ==============
    // Invariant: BHt/BMt hold eval i.
    #pragma unroll 1
    for (; i <= 64; ++i) {
        float4v C2t[4];
        tputC2(BHt, BMt, C2t);
        cm = fminf(cm, l3(C2t));
        if (i < 64)
            front(STEP_ * (float)(i + 1), BHt, BMt);
    }

    // ---- reflection net: quad q handles hidden j in [16q, 16q+16) ----
    const float px = fmaf(dx, cd, ox), py = fmaf(dy, cd, oy), pz = fmaf(dz, cd, oz);
    float r0 = 0.f, r1 = 0.f, r2 = 0.f;
    #pragma unroll 4
    for (int jj = 0; jj < 16; ++jj) {
        int j = quad * 16 + jj;
        float a = fmaf(px, Wr0[j],
                  fmaf(py, Wr0[64 + j],
                  fmaf(pz, Wr0[128 + j],
                  fmaf(dx, Wr0[192 + j],
                  fmaf(dy, Wr0[256 + j],
                  fmaf(dz, Wr0[320 + j], br0[j]))))));
        a = fmaxf(a, 0.f);
        r0 = fmaf(a, Wr1[j * 3 + 0], r0);
        r1 = fmaf(a, Wr1[j * 3 + 1], r1);
        r2 = fmaf(a, Wr1[j * 3 + 2], r2);
    }
    r0 = xor16_sum(r0); r0 = xor32_sum(r0);
    r1 = xor16_sum(r1); r1 = xor32_sum(r1);
    r2 = xor16_sum(r2); r2 = xor32_sum(r2);
    r0 = 1.f / (1.f + expf(-(r0 + br1[0])));
    r1 = 1.f / (1.f + expf(-(r1 + br1[1])));
    r2 = 1.f / (1.f + expf(-(r2 + br1[2])));
    if (!hit) { r0 = 0.f; r1 = 0.f; r2 = 0.f; }
    if (lane < 16) {
        // one coalesced float4 store: rgb + tput
        float4v o4 = {r0, r1, r2, cm};
        *reinterpret_cast<float4v*>(out + (rayBase + lane) * 4) = o4;
    }
}

extern "C" void kernel_launch(void* const* d_in, const int* in_sizes, int n_in,
                              void* d_out, int out_size, void* d_ws, size_t ws_size,
                              hipStream_t stream) {
    const float* rays = (const float*)d_in[0];
    const float* W0   = (const float*)d_in[1];
    const float* b0   = (const float*)d_in[2];
    const float* W1   = (const float*)d_in[3];
    const float* b1   = (const float*)d_in[4];
    const float* W2   = (const float*)d_in[5];
    const float* b2   = (const float*)d_in[6];
    const float* Wr0  = (const float*)d_in[7];
    const float* br0  = (const float*)d_in[8];
    const float* Wr1  = (const float*)d_in[9];
    const float* br1  = (const float*)d_in[10];
    float* out = (float*)d_out;

    // 2048 single-wave blocks, 16 rays each, march+tput fused per wave.
    // R25: independent per-product MFMA accumulators (march depth 6->2,
    // tput 4->2) + pk-f32 combine -- attacks dependent-MFMA latency,
    // the one unmeasured term that can explain the ~2700 cyc/iter stall.
    // Zero LDS; waves_per_eu(2,2): 2/SIMD, 256-reg budget pinned.
    hipLaunchKernelGGL(sdf_w14_k, dim3(NRAYS / 16), dim3(64), 0, stream,
                       rays, W0, b0, W1, b1, W2, b2, Wr0, br0, Wr1, br1, out);
}

// Round 12
// 165.828 us; speedup vs baseline: 1.0484x; 1.0484x over previous
//
#include <hip/hip_runtime.h>
#include <math.h>

// Problem constants
#define NRAYS        32768
#define MARCH_ITERS  64
#define EPS_         1e-4f
#define STEP_        ((1.0f + 1.0f/64.0f) / 64.0f)   // exact in fp32

typedef __attribute__((ext_vector_type(8)))  short    short8;   // 8 bf16
typedef __attribute__((ext_vector_type(4)))  float    float4v;  // C/D frag
typedef __attribute__((ext_vector_type(2)))  float    float2v;  // pk-f32 pair
typedef __attribute__((ext_vector_type(4)))  unsigned uint4v;
typedef __attribute__((ext_vector_type(2)))  unsigned uint2v;

__device__ __forceinline__ short8 mk_frag(unsigned p0, unsigned p1,
                                          unsigned p2, unsigned p3) {
    uint4v v = {p0, p1, p2, p3};
    return __builtin_bit_cast(short8, v);
}

// One v_perm_b32: low16 = trunc-bf16(a), high16 = trunc-bf16(b).
__device__ __forceinline__ unsigned packbf(unsigned a, unsigned b) {
    return __builtin_amdgcn_perm(b, a, 0x07060302u);
}

// 2-way split: hi + residual (packbf of r truncates -> the mid limb).
struct Split2 { unsigned h, r; };
__device__ __forceinline__ Split2 split2(float x) {
    unsigned xu = __float_as_uint(x);
    float xh = __uint_as_float(xu & 0xFFFF0000u);
    float rr = x - xh;                        // exact residual
    return { xu, __float_as_uint(rr) };
}

// packed f32 fma -> v_pk_fma_f32 (lane-exact == 2 scalar v_fma_f32)
__device__ __forceinline__ float2v fma2(float2v a, float2v b, float2v c) {
    return __builtin_elementwise_fma(a, b, c);
}

// R26 butterflies: permlane-swap BUILTINS (VALU, ~4-8 cyc) replacing the
// DS-based reduces (swizzle/bpermute, ~120 cyc round-trips each). With
// a = b = x, v_permlane{16,32}_swap exchanges complementary row-groups
// between the two outputs, so each lane holds exactly {x[l], x[l^N]}
// across the pair -> out.x + out.y is BIT-IDENTICAL to x + shfl_xor(x,N)
// by fp-add commutativity, for either exchange direction. R23's failure
// was the inline-asm "+v" form (regalloc tie-coalesced the two operands
// -> self-swap); the builtin returns both halves explicitly (V2Ui), so
// the compiler allocates correctly (guide T12/m214v22/m255: builtin
// exists and is verified on gfx950). __has_builtin fallback = R24's
// verified swizzle/shfl primitives (still PASS, perf ~R24).
__device__ __forceinline__ float xor16_sum(float x) {
#if __has_builtin(__builtin_amdgcn_permlane16_swap)
    unsigned u = __float_as_uint(x);
    uint2v r = __builtin_amdgcn_permlane16_swap(u, u, false, false);
    return __uint_as_float(r.x) + __uint_as_float(r.y);
#else
    float p = __int_as_float(
        __builtin_amdgcn_ds_swizzle(__float_as_int(x), 0x401F));
    return x + p;
#endif
}
__device__ __forceinline__ float xor32_sum(float x) {
#if __has_builtin(__builtin_amdgcn_permlane32_swap)
    unsigned u = __float_as_uint(x);
    uint2v r = __builtin_amdgcn_permlane32_swap(u, u, false, false);
    return __uint_as_float(r.x) + __uint_as_float(r.y);
#else
    return x + __shfl_xor(x, 32, 64);
#endif
}

// R26 = R22 base (best measured, 114us) + permlane butterflies; R25's
// split accumulators reverted (null, cost insts/regs). R25 post-mortem:
// breaking MFMA C-chains was null -> chained-acc MFMAs already issue at
// pipe rate. Remaining identified span term: 4 serialized DS ops/iter
// (l3_m swizzle+bpermute on the march critical path, then l3_t's pair,
// which in-order issue can't start until l3_m's result is consumed) ~
// 480+ cyc of the ~4.4k cyc/iter span. This round removes ALL DS from
// the loop. Arithmetic bit-identical to R22 -> absmax exactly
// 0.00390625 expected.
// 2048 single-wave blocks, 16 rays each, march+tput fused per wave
// (R22): the tput stream's 65 independent evals fill the march chain's
// in-order stall slots. Zero LDS; waves_per_eu(2,8).
// MFMA layouts (R6-verified): A[row=lane&15][k=quad*8+j],
// B[k=quad*8+j][col=lane&15], C/D col=lane&15 row=quad*4+reg.
// Precision: march L2 = 3 products (m,h)(h,m)(h,h); tput L2 = 2 products.
__global__ __launch_bounds__(64)
__attribute__((amdgpu_waves_per_eu(2, 8)))
void sdf_w15_k(
    const float* __restrict__ rays,
    const float* __restrict__ W0,  const float* __restrict__ b0,
    const float* __restrict__ W1,  const float* __restrict__ b1,
    const float* __restrict__ W2,  const float* __restrict__ b2,
    const float* __restrict__ Wr0, const float* __restrict__ br0,
    const float* __restrict__ Wr1, const float* __restrict__ br1,
    float* __restrict__ out)
{
    const int lane = threadIdx.x;             // 0..63, one wave per block
    const int quad = lane >> 4;
    const int m    = lane & 15;
    const int rayBase = blockIdx.x * 16;

    // ---- per-lane ray (ray = rayBase + m, replicated over quads) ----
    const float* rp = rays + (rayBase + m) * 6;
    const float ox = rp[0], oy = rp[1], oz = rp[2];
    const float dx = rp[3], dy = rp[4], dz = rp[5];

    // ---- linear-L1 coefficients (R21): L1 pre-act = a + c*s ----
    float2v a2[4][2], s2[4][2];
    #pragma unroll
    for (int t = 0; t < 4; ++t)
        #pragma unroll
        for (int p = 0; p < 2; ++p) {
            float av[2], sv[2];
            #pragma unroll
            for (int e = 0; e < 2; ++e) {
                int j = 32 * (t >> 1) + 8 * quad + 4 * (t & 1) + (2 * p + e);
                float w0c = W0[j], w1c = W0[64 + j], w2c = W0[128 + j];
                av[e] = fmaf(ox, w0c, fmaf(oy, w1c, fmaf(oz, w2c, b0[j])));
                sv[e] = fmaf(dx, w0c, fmaf(dy, w1c, dz * w2c));
            }
            a2[t][p] = (float2v){av[0], av[1]};
            s2[t][p] = (float2v){sv[0], sv[1]};
        }

    // ---- b1 (first-product C-input) and W2 (L3), rows j2 = 16t+4q+r ----
    float4v b1v[4];
    float2v w2a[4], w2b[4];
    #pragma unroll
    for (int t = 0; t < 4; ++t) {
        int base = 16 * t + 4 * quad;
        b1v[t] = (float4v){b1[base], b1[base + 1], b1[base + 2], b1[base + 3]};
        w2a[t] = (float2v){W2[base], W2[base + 1]};
        w2b[t] = (float2v){W2[base + 2], W2[base + 3]};
    }
    const float b2s = b2[0];

    // ---- W1 limbs: A2h (hi) + A2m (mid), 64 regs, shared by streams ----
    short8 A2h[2][4], A2m[2][4];
    #pragma unroll
    for (int h = 0; h < 2; ++h)
        #pragma unroll
        for (int t = 0; t < 4; ++t) {
            unsigned pm[4], ph[4];
            #pragma unroll
            for (int jp = 0; jp < 4; ++jp) {
                int k0 = 32 * h + quad * 8 + 2 * jp;
                int j2 = 16 * t + m;
                Split2 a = split2(W1[k0 * 64 + j2]);
                Split2 b = split2(W1[(k0 + 1) * 64 + j2]);
                pm[jp] = packbf(a.r, b.r);   // trunc(residual) == mid limb
                ph[jp] = packbf(a.h, b.h);   // trunc(full) == hi limb
            }
            A2m[h][t] = mk_frag(pm[0], pm[1], pm[2], pm[3]);
            A2h[h][t] = mk_frag(ph[0], ph[1], ph[2], ph[3]);
        }

    // ---- shared front-end: c -> L1 = relu(a + c*s) -> split2 pack ----
    const float2v z2 = {0.f, 0.f};
    auto front = [&](float cv, short8* BH, short8* BM) {
        const float2v c2 = {cv, cv};
        unsigned PH[4][2], PM[4][2];
        #pragma unroll
        for (int t = 0; t < 4; ++t) {
            float2v v01 = fma2(c2, s2[t][0], a2[t][0]);
            float2v v23 = fma2(c2, s2[t][1], a2[t][1]);
            v01 = __builtin_elementwise_max(v01, z2);
            v23 = __builtin_elementwise_max(v23, z2);
            unsigned u0 = __float_as_uint(v01.x), u1 = __float_as_uint(v01.y);
            unsigned u2 = __float_as_uint(v23.x), u3 = __float_as_uint(v23.y);
            PH[t][0] = packbf(u0, u1); PH[t][1] = packbf(u2, u3);
            float2v h01 = {__uint_as_float(u0 & 0xFFFF0000u),
                           __uint_as_float(u1 & 0xFFFF0000u)};
            float2v h23 = {__uint_as_float(u2 & 0xFFFF0000u),
                           __uint_as_float(u3 & 0xFFFF0000u)};
            float2v r01 = v01 - h01;   // pk sub, exact residual
            float2v r23 = v23 - h23;
            PM[t][0] = packbf(__float_as_uint(r01.x), __float_as_uint(r01.y));
            PM[t][1] = packbf(__float_as_uint(r23.x), __float_as_uint(r23.y));
        }
        #pragma unroll
        for (int h = 0; h < 2; ++h) {
            BH[h] = mk_frag(PH[2 * h][0], PH[2 * h][1],
                            PH[2 * h + 1][0], PH[2 * h + 1][1]);
            BM[h] = mk_frag(PM[2 * h][0], PM[2 * h][1],
                            PM[2 * h + 1][0], PM[2 * h + 1][1]);
        }
    };

    // ---- L3: in-lane relu*W2 (pk fma), permlane butterflies (no DS) ----
    auto l3 = [&](const float4v* C2) -> float {
        float2v q01 = {0.f, 0.f}, q23 = {0.f, 0.f};
        #pragma unroll
        for (int t = 0; t < 4; ++t) {
            float2v rel01 = __builtin_elementwise_max(
                (float2v){C2[t][0], C2[t][1]}, z2);
            float2v rel23 = __builtin_elementwise_max(
                (float2v){C2[t][2], C2[t][3]}, z2);
            q01 = fma2(rel01, w2a[t], q01);
            q23 = fma2(rel23, w2b[t], q23);
        }
        float part = (q01.x + q01.y) + (q23.x + q23.y);
        part = xor16_sum(part);                // == part + shfl_xor(part,16)
        part = xor32_sum(part);                // == part + shfl_xor(part,32)
        return b2s + part;
    };

    // tput L2: 2 products (h,m)(h,h), b1 folded into first. R22 chained.
    auto tputC2 = [&](const short8* BHt, const short8* BMt, float4v* C2t) {
        #pragma unroll
        for (int t = 0; t < 4; ++t)
            C2t[t] = __builtin_amdgcn_mfma_f32_16x16x32_bf16(
                A2h[0][t], BMt[0], b1v[t], 0, 0, 0);
        #pragma unroll
        for (int t = 0; t < 4; ++t)
            C2t[t] = __builtin_amdgcn_mfma_f32_16x16x32_bf16(
                A2h[1][t], BMt[1], C2t[t], 0, 0, 0);
        #pragma unroll
        for (int h = 0; h < 2; ++h)
            #pragma unroll
            for (int t = 0; t < 4; ++t)
                C2t[t] = __builtin_amdgcn_mfma_f32_16x16x32_bf16(
                    A2h[h][t], BHt[h], C2t[t], 0, 0, 0);
    };

    bool  hit = false;
    float cd  = 0.f;
    float cm  = 3.4e38f;
    int   i   = 0;

    // =========== FUSED loop: march iter i (i<64) + tput eval i ===========
    #pragma unroll 1
    for (; i <= 64; ++i) {
        if (i >= MARCH_ITERS || __all(hit)) break;   // -> tput-only remainder
        // 1) tput front first: independent work covering the backedge
        //    latency of the march chain (l3_m of iter i-1 -> cd -> front_m).
        float ti = STEP_ * (float)i;
        short8 BHt[2], BMt[2];
        front(ti, BHt, BMt);
        // 2) march front (needs cd)
        short8 BHm[2], BMm[2];
        front(cd, BHm, BMm);
        // 3) march MFMAs first (6 stages), so C2m is deep in the pipe
        //    before l3_m reads it; tput MFMAs (4 stages) issue meanwhile.
        float4v C2m[4], C2t[4];
        #pragma unroll
        for (int t = 0; t < 4; ++t)
            C2m[t] = __builtin_amdgcn_mfma_f32_16x16x32_bf16(
                A2m[0][t], BHm[0], b1v[t], 0, 0, 0);
        #pragma unroll
        for (int t = 0; t < 4; ++t)
            C2m[t] = __builtin_amdgcn_mfma_f32_16x16x32_bf16(
                A2m[1][t], BHm[1], C2m[t], 0, 0, 0);
        #pragma unroll
        for (int h = 0; h < 2; ++h)
            #pragma unroll
            for (int t = 0; t < 4; ++t)
                C2m[t] = __builtin_amdgcn_mfma_f32_16x16x32_bf16(
                    A2h[h][t], BMm[h], C2m[t], 0, 0, 0);
        #pragma unroll
        for (int h = 0; h < 2; ++h)
            #pragma unroll
            for (int t = 0; t < 4; ++t)
                C2m[t] = __builtin_amdgcn_mfma_f32_16x16x32_bf16(
                    A2h[h][t], BHm[h], C2m[t], 0, 0, 0);
        tputC2(BHt, BMt, C2t);
        // 4) march finish (serial chain, now DS-free) while tput drains
        float dm = l3(C2m);
        bool c = (dm < EPS_) && (cd >= 0.f) && (cd <= 1.f);
        hit = hit || c;
        if (!hit) cd += dm;
        // 5) tput finish
        cm = fminf(cm, l3(C2t));
    }

    // =========== tput-only remainder (march done / all-hit) ==============
    #pragma unroll 1
    for (; i <= 64; ++i) {
        float ti = STEP_ * (float)i;
        short8 BHt[2], BMt[2];
        front(ti, BHt, BMt);
        float4v C2t[4];
        tputC2(BHt, BMt, C2t);
        cm = fminf(cm, l3(C2t));
    }

    // ---- reflection net: quad q handles hidden j in [16q, 16q+16) ----
    const float px = fmaf(dx, cd, ox), py = fmaf(dy, cd, oy), pz = fmaf(dz, cd, oz);
    float r0 = 0.f, r1 = 0.f, r2 = 0.f;
    #pragma unroll 4
    for (int jj = 0; jj < 16; ++jj) {
        int j = quad * 16 + jj;
        float a = fmaf(px, Wr0[j],
                  fmaf(py, Wr0[64 + j],
                  fmaf(pz, Wr0[128 + j],
                  fmaf(dx, Wr0[192 + j],
                  fmaf(dy, Wr0[256 + j],
                  fmaf(dz, Wr0[320 + j], br0[j]))))));
        a = fmaxf(a, 0.f);
        r0 = fmaf(a, Wr1[j * 3 + 0], r0);
        r1 = fmaf(a, Wr1[j * 3 + 1], r1);
        r2 = fmaf(a, Wr1[j * 3 + 2], r2);
    }
    r0 = xor16_sum(r0); r0 = xor32_sum(r0);
    r1 = xor16_sum(r1); r1 = xor32_sum(r1);
    r2 = xor16_sum(r2); r2 = xor32_sum(r2);
    r0 = 1.f / (1.f + expf(-(r0 + br1[0])));
    r1 = 1.f / (1.f + expf(-(r1 + br1[1])));
    r2 = 1.f / (1.f + expf(-(r2 + br1[2])));
    if (!hit) { r0 = 0.f; r1 = 0.f; r2 = 0.f; }
    if (lane < 16) {
        // one coalesced float4 store: rgb + tput
        float4v o4 = {r0, r1, r2, cm};
        *reinterpret_cast<float4v*>(out + (rayBase + lane) * 4) = o4;
    }
}

extern "C" void kernel_launch(void* const* d_in, const int* in_sizes, int n_in,
                              void* d_out, int out_size, void* d_ws, size_t ws_size,
                              hipStream_t stream) {
    const float* rays = (const float*)d_in[0];
    const float* W0   = (const float*)d_in[1];
    const float* b0   = (const float*)d_in[2];
    const float* W1   = (const float*)d_in[3];
    const float* b1   = (const float*)d_in[4];
    const float* W2   = (const float*)d_in[5];
    const float* b2   = (const float*)d_in[6];
    const float* Wr0  = (const float*)d_in[7];
    const float* br0  = (const float*)d_in[8];
    const float* Wr1  = (const float*)d_in[9];
    const float* br1  = (const float*)d_in[10];
    float* out = (float*)d_out;

    // 2048 single-wave blocks, 16 rays each, march+tput fused per wave
    // (R22 base). R26: permlane-swap builtin butterflies -> the loop is
    // now entirely DS-free; both ~120-cyc reduce round-trips leave the
    // march critical path. Zero LDS; waves_per_eu(2,8).
    hipLaunchKernelGGL(sdf_w15_k, dim3(NRAYS / 16), dim3(64), 0, stream,
                       rays, W0, b0, W1, b1, W2, b2, Wr0, br0, Wr1, br1, out);
}

// Round 13
// 163.788 us; speedup vs baseline: 1.0614x; 1.0125x over previous
//
#include <hip/hip_runtime.h>
#include <math.h>

// Problem constants
#define NRAYS        32768
#define MARCH_ITERS  64
#define EPS_         1e-4f
#define STEP_        ((1.0f + 1.0f/64.0f) / 64.0f)   // exact in fp32

typedef __attribute__((ext_vector_type(8)))  short    short8;   // 8 bf16
typedef __attribute__((ext_vector_type(4)))  float    float4v;  // C/D frag
typedef __attribute__((ext_vector_type(2)))  float    float2v;  // pk-f32 pair
typedef __attribute__((ext_vector_type(4)))  unsigned uint4v;
typedef __attribute__((ext_vector_type(2)))  unsigned uint2v;

__device__ __forceinline__ short8 mk_frag(unsigned p0, unsigned p1,
                                          unsigned p2, unsigned p3) {
    uint4v v = {p0, p1, p2, p3};
    return __builtin_bit_cast(short8, v);
}

// One v_perm_b32: low16 = trunc-bf16(a), high16 = trunc-bf16(b).
__device__ __forceinline__ unsigned packbf(unsigned a, unsigned b) {
    return __builtin_amdgcn_perm(b, a, 0x07060302u);
}

// 2-way split: hi + residual (packbf of r truncates -> the mid limb).
struct Split2 { unsigned h, r; };
__device__ __forceinline__ Split2 split2(float x) {
    unsigned xu = __float_as_uint(x);
    float xh = __uint_as_float(xu & 0xFFFF0000u);
    float rr = x - xh;                        // exact residual
    return { xu, __float_as_uint(rr) };
}

// packed f32 fma -> v_pk_fma_f32 (lane-exact == 2 scalar v_fma_f32)
__device__ __forceinline__ float2v fma2(float2v a, float2v b, float2v c) {
    return __builtin_elementwise_fma(a, b, c);
}

// Butterflies via permlane-swap builtins (R26-verified: PASS, bit-identical
// to shfl_xor by fp-add commutativity). Fallback = R24's verified DS forms.
__device__ __forceinline__ float xor16_sum(float x) {
#if __has_builtin(__builtin_amdgcn_permlane16_swap)
    unsigned u = __float_as_uint(x);
    uint2v r = __builtin_amdgcn_permlane16_swap(u, u, false, false);
    return __uint_as_float(r.x) + __uint_as_float(r.y);
#else
    float p = __int_as_float(
        __builtin_amdgcn_ds_swizzle(__float_as_int(x), 0x401F));
    return x + p;
#endif
}
__device__ __forceinline__ float xor32_sum(float x) {
#if __has_builtin(__builtin_amdgcn_permlane32_swap)
    unsigned u = __float_as_uint(x);
    uint2v r = __builtin_amdgcn_permlane32_swap(u, u, false, false);
    return __uint_as_float(r.x) + __uint_as_float(r.y);
#else
    return x + __shfl_xor(x, 32, 64);
#endif
}

// R27: delete the per-iteration early-exit; fixed 64 iters + unroll 2.
// R26 ledger: per-SIMD span ~4190 cyc/iter vs ~1550 matrix + ~1100 VALU
// of accountable pipe work; every DATAFLOW lever (occupancy R20, inst
// count R21, fusion R22, pipelining R24, MFMA chains R25, DS removal
// R26) probed; only fusion (+12%) and permlane (+2%) moved. The one
// untouched structure: the fused loop's `if (__all(hit)) break` -- a
// conditional EXIT at every iteration boundary that the compiler cannot
// move code across, so no cross-iteration scheduling ever happened
// (R24's manual pipeline kept the break -> could only move front_t).
// The break is semantically unnecessary: the reference scan runs fixed
// 64 iterations and our updates are predicated (hit latches, cd frozen)
// -- extra iterations are exact no-ops. Makespan is set by waves that
// never all-hit (any 1/16 rays missing -> full 64), so the break only
// saved time off the critical path. Removing it + #pragma unroll 2
// makes the body branch-free except the backedge: iter i+1's tput
// front + 16 independent MFMAs (~430 cyc of guaranteed-ready work) can
// fill iter i's march tail (l3_m -> cd -> front_m).
// Arithmetic bit-identical to R26 (same ops, same per-stream order;
// control flow only) -> absmax must stay exactly 0.00390625.
// 2048 single-wave blocks, 16 rays each, march+tput fused per wave.
// Zero LDS; zero DS in the loop; waves_per_eu(2,8).
// MFMA layouts (R6-verified): A[row=lane&15][k=quad*8+j],
// B[k=quad*8+j][col=lane&15], C/D col=lane&15 row=quad*4+reg.
// Precision: march L2 = 3 products (m,h)(h,m)(h,h); tput L2 = 2 products.
__global__ __launch_bounds__(64)
__attribute__((amdgpu_waves_per_eu(2, 8)))
void sdf_w16_k(
    const float* __restrict__ rays,
    const float* __restrict__ W0,  const float* __restrict__ b0,
    const float* __restrict__ W1,  const float* __restrict__ b1,
    const float* __restrict__ W2,  const float* __restrict__ b2,
    const float* __restrict__ Wr0, const float* __restrict__ br0,
    const float* __restrict__ Wr1, const float* __restrict__ br1,
    float* __restrict__ out)
{
    const int lane = threadIdx.x;             // 0..63, one wave per block
    const int quad = lane >> 4;
    const int m    = lane & 15;
    const int rayBase = blockIdx.x * 16;

    // ---- per-lane ray (ray = rayBase + m, replicated over quads) ----
    const float* rp = rays + (rayBase + m) * 6;
    const float ox = rp[0], oy = rp[1], oz = rp[2];
    const float dx = rp[3], dy = rp[4], dz = rp[5];

    // ---- linear-L1 coefficients (R21): L1 pre-act = a + c*s ----
    float2v a2[4][2], s2[4][2];
    #pragma unroll
    for (int t = 0; t < 4; ++t)
        #pragma unroll
        for (int p = 0; p < 2; ++p) {
            float av[2], sv[2];
            #pragma unroll
            for (int e = 0; e < 2; ++e) {
                int j = 32 * (t >> 1) + 8 * quad + 4 * (t & 1) + (2 * p + e);
                float w0c = W0[j], w1c = W0[64 + j], w2c = W0[128 + j];
                av[e] = fmaf(ox, w0c, fmaf(oy, w1c, fmaf(oz, w2c, b0[j])));
                sv[e] = fmaf(dx, w0c, fmaf(dy, w1c, dz * w2c));
            }
            a2[t][p] = (float2v){av[0], av[1]};
            s2[t][p] = (float2v){sv[0], sv[1]};
        }

    // ---- b1 (first-product C-input) and W2 (L3), rows j2 = 16t+4q+r ----
    float4v b1v[4];
    float2v w2a[4], w2b[4];
    #pragma unroll
    for (int t = 0; t < 4; ++t) {
        int base = 16 * t + 4 * quad;
        b1v[t] = (float4v){b1[base], b1[base + 1], b1[base + 2], b1[base + 3]};
        w2a[t] = (float2v){W2[base], W2[base + 1]};
        w2b[t] = (float2v){W2[base + 2], W2[base + 3]};
    }
    const float b2s = b2[0];

    // ---- W1 limbs: A2h (hi) + A2m (mid), 64 regs, shared by streams ----
    short8 A2h[2][4], A2m[2][4];
    #pragma unroll
    for (int h = 0; h < 2; ++h)
        #pragma unroll
        for (int t = 0; t < 4; ++t) {
            unsigned pm[4], ph[4];
            #pragma unroll
            for (int jp = 0; jp < 4; ++jp) {
                int k0 = 32 * h + quad * 8 + 2 * jp;
                int j2 = 16 * t + m;
                Split2 a = split2(W1[k0 * 64 + j2]);
                Split2 b = split2(W1[(k0 + 1) * 64 + j2]);
                pm[jp] = packbf(a.r, b.r);   // trunc(residual) == mid limb
                ph[jp] = packbf(a.h, b.h);   // trunc(full) == hi limb
            }
            A2m[h][t] = mk_frag(pm[0], pm[1], pm[2], pm[3]);
            A2h[h][t] = mk_frag(ph[0], ph[1], ph[2], ph[3]);
        }

    // ---- shared front-end: c -> L1 = relu(a + c*s) -> split2 pack ----
    const float2v z2 = {0.f, 0.f};
    auto front = [&](float cv, short8* BH, short8* BM) {
        const float2v c2 = {cv, cv};
        unsigned PH[4][2], PM[4][2];
        #pragma unroll
        for (int t = 0; t < 4; ++t) {
            float2v v01 = fma2(c2, s2[t][0], a2[t][0]);
            float2v v23 = fma2(c2, s2[t][1], a2[t][1]);
            v01 = __builtin_elementwise_max(v01, z2);
            v23 = __builtin_elementwise_max(v23, z2);
            unsigned u0 = __float_as_uint(v01.x), u1 = __float_as_uint(v01.y);
            unsigned u2 = __float_as_uint(v23.x), u3 = __float_as_uint(v23.y);
            PH[t][0] = packbf(u0, u1); PH[t][1] = packbf(u2, u3);
            float2v h01 = {__uint_as_float(u0 & 0xFFFF0000u),
                           __uint_as_float(u1 & 0xFFFF0000u)};
            float2v h23 = {__uint_as_float(u2 & 0xFFFF0000u),
                           __uint_as_float(u3 & 0xFFFF0000u)};
            float2v r01 = v01 - h01;   // pk sub, exact residual
            float2v r23 = v23 - h23;
            PM[t][0] = packbf(__float_as_uint(r01.x), __float_as_uint(r01.y));
            PM[t][1] = packbf(__float_as_uint(r23.x), __float_as_uint(r23.y));
        }
        #pragma unroll
        for (int h = 0; h < 2; ++h) {
            BH[h] = mk_frag(PH[2 * h][0], PH[2 * h][1],
                            PH[2 * h + 1][0], PH[2 * h + 1][1]);
            BM[h] = mk_frag(PM[2 * h][0], PM[2 * h][1],
                            PM[2 * h + 1][0], PM[2 * h + 1][1]);
        }
    };

    // ---- L3: in-lane relu*W2 (pk fma), permlane butterflies (no DS) ----
    auto l3 = [&](const float4v* C2) -> float {
        float2v q01 = {0.f, 0.f}, q23 = {0.f, 0.f};
        #pragma unroll
        for (int t = 0; t < 4; ++t) {
            float2v rel01 = __builtin_elementwise_max(
                (float2v){C2[t][0], C2[t][1]}, z2);
            float2v rel23 = __builtin_elementwise_max(
                (float2v){C2[t][2], C2[t][3]}, z2);
            q01 = fma2(rel01, w2a[t], q01);
            q23 = fma2(rel23, w2b[t], q23);
        }
        float part = (q01.x + q01.y) + (q23.x + q23.y);
        part = xor16_sum(part);                // == part + shfl_xor(part,16)
        part = xor32_sum(part);                // == part + shfl_xor(part,32)
        return b2s + part;
    };

    // tput L2: 2 products (h,m)(h,h), b1 folded into first. R22 chained.
    auto tputC2 = [&](const short8* BHt, const short8* BMt, float4v* C2t) {
        #pragma unroll
        for (int t = 0; t < 4; ++t)
            C2t[t] = __builtin_amdgcn_mfma_f32_16x16x32_bf16(
                A2h[0][t], BMt[0], b1v[t], 0, 0, 0);
        #pragma unroll
        for (int t = 0; t < 4; ++t)
            C2t[t] = __builtin_amdgcn_mfma_f32_16x16x32_bf16(
                A2h[1][t], BMt[1], C2t[t], 0, 0, 0);
        #pragma unroll
        for (int h = 0; h < 2; ++h)
            #pragma unroll
            for (int t = 0; t < 4; ++t)
                C2t[t] = __builtin_amdgcn_mfma_f32_16x16x32_bf16(
                    A2h[h][t], BHt[h], C2t[t], 0, 0, 0);
    };

    bool  hit = false;
    float cd  = 0.f;
    float cm  = 3.4e38f;

    // =========== FUSED loop: FIXED 64 iters, branch-free body ============
    // No early exit: updates are predicated (hit latches, cd frozen), so
    // post-all-hit iterations are exact no-ops -- matching the reference
    // scan's fixed trip count. unroll 2 lets the scheduler weave iter
    // i+1's independent tput work into iter i's march tail.
    #pragma unroll 2
    for (int i = 0; i < MARCH_ITERS; ++i) {
        // 1) tput front (independent filler for the march backedge chain)
        float ti = STEP_ * (float)i;
        short8 BHt[2], BMt[2];
        front(ti, BHt, BMt);
        // 2) march front (needs cd)
        short8 BHm[2], BMm[2];
        front(cd, BHm, BMm);
        // 3) march MFMAs first, tput MFMAs behind them
        float4v C2m[4], C2t[4];
        #pragma unroll
        for (int t = 0; t < 4; ++t)
            C2m[t] = __builtin_amdgcn_mfma_f32_16x16x32_bf16(
                A2m[0][t], BHm[0], b1v[t], 0, 0, 0);
        #pragma unroll
        for (int t = 0; t < 4; ++t)
            C2m[t] = __builtin_amdgcn_mfma_f32_16x16x32_bf16(
                A2m[1][t], BHm[1], C2m[t], 0, 0, 0);
        #pragma unroll
        for (int h = 0; h < 2; ++h)
            #pragma unroll
            for (int t = 0; t < 4; ++t)
                C2m[t] = __builtin_amdgcn_mfma_f32_16x16x32_bf16(
                    A2h[h][t], BMm[h], C2m[t], 0, 0, 0);
        #pragma unroll
        for (int h = 0; h < 2; ++h)
            #pragma unroll
            for (int t = 0; t < 4; ++t)
                C2m[t] = __builtin_amdgcn_mfma_f32_16x16x32_bf16(
                    A2h[h][t], BHm[h], C2m[t], 0, 0, 0);
        tputC2(BHt, BMt, C2t);
        // 4) march finish (serial chain; tput MFMAs drain underneath)
        float dm = l3(C2m);
        bool c = (dm < EPS_) && (cd >= 0.f) && (cd <= 1.f);
        hit = hit || c;
        if (!hit) cd += dm;                    // predicated: v_cndmask
        // 5) tput finish
        cm = fminf(cm, l3(C2t));
    }

    // =========== trailing tput eval i = 64 ===============================
    {
        short8 BHt[2], BMt[2];
        front(STEP_ * 64.0f, BHt, BMt);
        float4v C2t[4];
        tputC2(BHt, BMt, C2t);
        cm = fminf(cm, l3(C2t));
    }

    // ---- reflection net: quad q handles hidden j in [16q, 16q+16) ----
    const float px = fmaf(dx, cd, ox), py = fmaf(dy, cd, oy), pz = fmaf(dz, cd, oz);
    float r0 = 0.f, r1 = 0.f, r2 = 0.f;
    #pragma unroll 4
    for (int jj = 0; jj < 16; ++jj) {
        int j = quad * 16 + jj;
        float a = fmaf(px, Wr0[j],
                  fmaf(py, Wr0[64 + j],
                  fmaf(pz, Wr0[128 + j],
                  fmaf(dx, Wr0[192 + j],
                  fmaf(dy, Wr0[256 + j],
                  fmaf(dz, Wr0[320 + j], br0[j]))))));
        a = fmaxf(a, 0.f);
        r0 = fmaf(a, Wr1[j * 3 + 0], r0);
        r1 = fmaf(a, Wr1[j * 3 + 1], r1);
        r2 = fmaf(a, Wr1[j * 3 + 2], r2);
    }
    r0 = xor16_sum(r0); r0 = xor32_sum(r0);
    r1 = xor16_sum(r1); r1 = xor32_sum(r1);
    r2 = xor16_sum(r2); r2 = xor32_sum(r2);
    r0 = 1.f / (1.f + expf(-(r0 + br1[0])));
    r1 = 1.f / (1.f + expf(-(r1 + br1[1])));
    r2 = 1.f / (1.f + expf(-(r2 + br1[2])));
    if (!hit) { r0 = 0.f; r1 = 0.f; r2 = 0.f; }
    if (lane < 16) {
        // one coalesced float4 store: rgb + tput
        float4v o4 = {r0, r1, r2, cm};
        *reinterpret_cast<float4v*>(out + (rayBase + lane) * 4) = o4;
    }
}

extern "C" void kernel_launch(void* const* d_in, const int* in_sizes, int n_in,
                              void* d_out, int out_size, void* d_ws, size_t ws_size,
                              hipStream_t stream) {
    const float* rays = (const float*)d_in[0];
    const float* W0   = (const float*)d_in[1];
    const float* b0   = (const float*)d_in[2];
    const float* W1   = (const float*)d_in[3];
    const float* b1   = (const float*)d_in[4];
    const float* W2   = (const float*)d_in[5];
    const float* b2   = (const float*)d_in[6];
    const float* Wr0  = (const float*)d_in[7];
    const float* br0  = (const float*)d_in[8];
    const float* Wr1  = (const float*)d_in[9];
    const float* br1  = (const float*)d_in[10];
    float* out = (float*)d_out;

    // 2048 single-wave blocks, 16 rays each, march+tput fused per wave.
    // R27: fixed-64 branch-free fused loop (early-exit removed; it was a
    // scheduling barrier and only saved time off the critical path) +
    // unroll 2 -> cross-iteration overlap finally expressible.
    // Zero LDS; zero DS in loop; waves_per_eu(2,8).
    hipLaunchKernelGGL(sdf_w16_k, dim3(NRAYS / 16), dim3(64), 0, stream,
                       rays, W0, b0, W1, b1, W2, b2, Wr0, br0, Wr1, br1, out);
}